// Round 1
// baseline (2802.295 us; speedup 1.0000x reference)
//
#include <hip/hip_runtime.h>
#include <cstdint>
#include <cstddef>

#define DEVI static __device__ __forceinline__

DEVI float sp_softplus(float x) { return x > 20.f ? x : log1pf(__expf(x)); }
DEVI float silu_f(float x)      { return x / (1.f + __expf(-x)); }

// ---------------- LayerNorm: one wave per row of 512 ----------------
template<bool RELU>
__global__ __launch_bounds__(256) void ln_k(const float* __restrict__ x,
                                            const float* __restrict__ g,
                                            const float* __restrict__ b,
                                            float* __restrict__ y, int M)
{
    int wid  = threadIdx.x >> 6;
    int lane = threadIdx.x & 63;
    int row  = blockIdx.x * 4 + wid;
    if (row >= M) return;
    const float* xr = x + (size_t)row * 512;
    float4 v0 = *(const float4*)(xr + lane * 8);
    float4 v1 = *(const float4*)(xr + lane * 8 + 4);
    float vals[8] = {v0.x, v0.y, v0.z, v0.w, v1.x, v1.y, v1.z, v1.w};
    float s = 0.f;
#pragma unroll
    for (int i = 0; i < 8; i++) s += vals[i];
#pragma unroll
    for (int off = 1; off < 64; off <<= 1) s += __shfl_xor(s, off);
    float mu = s * (1.f / 512.f);
    float q = 0.f;
#pragma unroll
    for (int i = 0; i < 8; i++) { float d = vals[i] - mu; q += d * d; }
#pragma unroll
    for (int off = 1; off < 64; off <<= 1) q += __shfl_xor(q, off);
    float rstd = rsqrtf(q * (1.f / 512.f) + 1e-5f);
    float* yr = y + (size_t)row * 512;
#pragma unroll
    for (int i = 0; i < 8; i++) {
        int c = lane * 8 + i;
        float o = (vals[i] - mu) * rstd * g[c] + b[c];
        if (RELU) o = fmaxf(o, 0.f);
        yr[c] = o;
    }
}

// ---------------- generic fp32 tiled GEMM: C = A(MxK) @ B(KxN) ----------------
// epilogue: optional bias, ACT(0 none, 1 softplus), optional residual add
template<bool BIAS, int ACT, bool RES>
__global__ __launch_bounds__(256) void gemm_f32(
    const float* __restrict__ A, int lda,
    const float* __restrict__ B, int ldb,
    const float* __restrict__ bias,
    const float* __restrict__ R, int ldr,
    float* __restrict__ C, int ldc,
    int M, int N, int K)
{
    const int BM = 64, BN = 64, BK = 16;
    __shared__ float As[BK][BM + 4];   // [16][68] transposed, float4-aligned
    __shared__ float Bs[BK][BN];       // [16][64]
    int bm = blockIdx.y * BM, bn = blockIdx.x * BN;
    int tid = threadIdx.x;
    int tx = tid & 15, ty = tid >> 4;
    float acc[4][4] = {};
    for (int k0 = 0; k0 < K; k0 += BK) {
#pragma unroll
        for (int i = 0; i < 4; i++) {
            int lin = tid + i * 256;
            int m = lin >> 4, k = lin & 15;
            int gm = bm + m, gk = k0 + k;
            float v = 0.f;
            if (gm < M && gk < K) v = A[(size_t)gm * lda + gk];
            As[k][m] = v;
        }
#pragma unroll
        for (int i = 0; i < 4; i++) {
            int lin = tid + i * 256;
            int k = lin >> 6, n = lin & 63;
            int gk = k0 + k, gn = bn + n;
            float v = 0.f;
            if (gk < K && gn < N) v = B[(size_t)gk * ldb + gn];
            Bs[k][n] = v;
        }
        __syncthreads();
#pragma unroll
        for (int k = 0; k < BK; k++) {
            float4 av = *(const float4*)&As[k][ty * 4];
            float4 bv = *(const float4*)&Bs[k][tx * 4];
            float ar[4] = {av.x, av.y, av.z, av.w};
            float br[4] = {bv.x, bv.y, bv.z, bv.w};
#pragma unroll
            for (int i = 0; i < 4; i++)
#pragma unroll
                for (int j = 0; j < 4; j++) acc[i][j] += ar[i] * br[j];
        }
        __syncthreads();
    }
#pragma unroll
    for (int i = 0; i < 4; i++) {
        int gm = bm + ty * 4 + i;
        if (gm >= M) continue;
#pragma unroll
        for (int j = 0; j < 4; j++) {
            int gn = bn + tx * 4 + j;
            if (gn >= N) continue;
            float v = acc[i][j];
            if (BIAS) v += bias[gn];
            if (ACT == 1) v = sp_softplus(v);
            if (RES) v += R[(size_t)gm * ldr + gn];
            C[(size_t)gm * ldc + gn] = v;
        }
    }
}

// ---------------- causal depthwise conv (K=4) + SiLU ----------------
// input: xin half of xz (stride 2048), output xin buffer (stride 1024)
__global__ __launch_bounds__(256) void conv4_silu_k(const float* __restrict__ xz,
                                                    const float* __restrict__ w,
                                                    const float* __restrict__ bias,
                                                    float* __restrict__ xin)
{
    int e = blockIdx.x * 256 + threadIdx.x;   // 2000*1024
    if (e >= 2000 * 1024) return;
    int d = e & 1023;
    int row = e >> 10;
    int b = row >= 1000 ? 1 : 0;
    int t = row - b * 1000;
    float acc = bias[d];
#pragma unroll
    for (int k = 0; k < 4; k++) {
        int tt = t - 3 + k;
        if (tt >= 0) acc += xz[((size_t)(b * 1000 + tt)) * 2048 + d] * w[d * 4 + k];
    }
    xin[(size_t)row * 1024 + d] = silu_f(acc);
}

// ---------------- selective scan ----------------
// 16 channels x 16 states per 256-thread block; grid (64, B)
__global__ __launch_bounds__(256) void scan_k(const float* __restrict__ dt,
                                              const float* __restrict__ xin,
                                              const float* __restrict__ proj,
                                              const float* __restrict__ A_log,
                                              float* __restrict__ ys)
{
    const int TB = 50;
    __shared__ float s_dt[TB][16], s_x[TB][16], s_B[TB][16], s_C[TB][16], s_y[TB][16];
    int b  = blockIdx.y;
    int d0 = blockIdx.x * 16;
    int tid = threadIdx.x;
    int ch = tid >> 4, st = tid & 15;
    int d = d0 + ch;
    float a_s = -__expf(A_log[d * 16 + st]);
    float h = 0.f;
    int base = b * 1000;
    for (int t0 = 0; t0 < 1000; t0 += TB) {
        for (int lin = tid; lin < TB * 16; lin += 256) {
            int tt = lin >> 4, j = lin & 15;
            size_t row = (size_t)(base + t0 + tt);
            s_dt[tt][j] = dt[row * 1024 + d0 + j];
            s_x[tt][j]  = xin[row * 1024 + d0 + j];
            s_B[tt][j]  = proj[row * 64 + 32 + j];
            s_C[tt][j]  = proj[row * 64 + 48 + j];
        }
        __syncthreads();
        for (int tt = 0; tt < TB; tt++) {
            float dtv = s_dt[tt][ch];
            float xv  = s_x[tt][ch];
            float dA  = __expf(dtv * a_s);
            h = dA * h + dtv * xv * s_B[tt][st];
            float p = h * s_C[tt][st];
            p += __shfl_xor(p, 1);
            p += __shfl_xor(p, 2);
            p += __shfl_xor(p, 4);
            p += __shfl_xor(p, 8);
            if (st == 0) s_y[tt][ch] = p;
        }
        __syncthreads();
        for (int lin = tid; lin < TB * 16; lin += 256) {
            int tt = lin >> 4, j = lin & 15;
            ys[(size_t)(base + t0 + tt) * 1024 + d0 + j] = s_y[tt][j];
        }
        __syncthreads();
    }
}

// ---------------- gating: g = (ys + xin*Dp) * silu(z) (in-place on ys) ----------------
__global__ __launch_bounds__(256) void gate_k(float* __restrict__ ys,
                                              const float* __restrict__ xin,
                                              const float* __restrict__ xz,
                                              const float* __restrict__ Dp)
{
    int e = blockIdx.x * 256 + threadIdx.x;
    if (e >= 2000 * 1024) return;
    int d = e & 1023;
    int row = e >> 10;
    float z = xz[(size_t)row * 2048 + 1024 + d];
    ys[e] = (ys[e] + xin[e] * Dp[d]) * silu_f(z);
}

// ---------------- depthwise conv31 (same pad) + residual add ----------------
__global__ __launch_bounds__(256) void dcconv31_k(const float* __restrict__ ln,
                                                  const float* __restrict__ a,
                                                  const float* __restrict__ w,
                                                  const float* __restrict__ bias,
                                                  float* __restrict__ h)
{
    int e = blockIdx.x * 256 + threadIdx.x;   // 2000*512
    if (e >= 2000 * 512) return;
    int m = e & 511;
    int row = e >> 9;
    int b = row >= 1000 ? 1 : 0;
    int t = row - b * 1000;
    float acc = bias[m];
    const float* wr = w + m * 31;
#pragma unroll
    for (int k = 0; k < 31; k++) {
        int tt = t - 15 + k;
        if (tt >= 0 && tt < 1000)
            acc += ln[((size_t)(b * 1000 + tt)) * 512 + m] * wr[k];
    }
    h[e] = a[e] + acc;
}

// ---------------- seq_mask output ----------------
__global__ void mask_k(const int* __restrict__ lengths, float* __restrict__ out)
{
    int i = blockIdx.x * 256 + threadIdx.x;
    if (i >= 2000) return;
    out[i] = ((i % 1000) < lengths[i / 1000]) ? 1.f : 0.f;
}

extern "C" void kernel_launch(void* const* d_in, const int* in_sizes, int n_in,
                              void* d_out, int out_size, void* d_ws, size_t ws_size,
                              hipStream_t stream)
{
    const float* x       = (const float*)d_in[0];
    const int*   lengths = (const int*)  d_in[1];
    const float* w_in0   = (const float*)d_in[2];
    const float* ln_in_g = (const float*)d_in[3];
    const float* ln_in_b = (const float*)d_in[4];
    const float* ln1_g   = (const float*)d_in[5];
    const float* ln1_b   = (const float*)d_in[6];
    const float* W_inproj= (const float*)d_in[7];
    const float* conv_w  = (const float*)d_in[8];
    const float* conv_b  = (const float*)d_in[9];
    const float* W_xproj = (const float*)d_in[10];
    const float* W_dt    = (const float*)d_in[11];
    const float* b_dt    = (const float*)d_in[12];
    const float* A_log   = (const float*)d_in[13];
    const float* Dp      = (const float*)d_in[14];
    const float* W_mo    = (const float*)d_in[15];
    const float* ln2_g   = (const float*)d_in[16];
    const float* ln2_b   = (const float*)d_in[17];
    const float* dc_w    = (const float*)d_in[18];
    const float* dc_b    = (const float*)d_in[19];
    const float* w_out   = (const float*)d_in[20];
    const float* b_out   = (const float*)d_in[21];

    float* ws   = (float*)d_ws;
    float* h    = ws;                 // 2000*512
    float* lnb  = h    + 1024000;     // 2000*512
    float* xz   = lnb  + 1024000;     // 2000*2048
    float* xin  = xz   + 4096000;     // 2000*1024
    float* proj = xin  + 2048000;     // 2000*64
    float* dt   = proj + 128000;      // 2000*1024
    float* ys   = dt   + 2048000;     // 2000*1024
    float* a    = ys   + 2048000;     // 2000*512

    dim3 blk(256);
    auto gg = [](int M, int N) { return dim3((N + 63) / 64, (M + 63) / 64); };

    // input projection + LN + relu
    gemm_f32<false, 0, false><<<gg(2000, 512), blk, 0, stream>>>(
        x, 257, w_in0, 512, nullptr, nullptr, 0, lnb, 512, 2000, 512, 257);
    ln_k<true><<<500, 256, 0, stream>>>(lnb, ln_in_g, ln_in_b, h, 2000);

    for (int i = 0; i < 4; i++) {
        ln_k<false><<<500, 256, 0, stream>>>(h, ln1_g + i * 512, ln1_b + i * 512, lnb, 2000);
        gemm_f32<false, 0, false><<<gg(2000, 2048), blk, 0, stream>>>(
            lnb, 512, W_inproj + (size_t)i * 512 * 2048, 2048,
            nullptr, nullptr, 0, xz, 2048, 2000, 2048, 512);
        conv4_silu_k<<<8000, 256, 0, stream>>>(xz, conv_w + (size_t)i * 1024 * 4,
                                               conv_b + i * 1024, xin);
        gemm_f32<false, 0, false><<<gg(2000, 64), blk, 0, stream>>>(
            xin, 1024, W_xproj + (size_t)i * 1024 * 64, 64,
            nullptr, nullptr, 0, proj, 64, 2000, 64, 1024);
        gemm_f32<true, 1, false><<<gg(2000, 1024), blk, 0, stream>>>(
            proj, 64, W_dt + (size_t)i * 32 * 1024, 1024,
            b_dt + i * 1024, nullptr, 0, dt, 1024, 2000, 1024, 32);
        scan_k<<<dim3(64, 2), 256, 0, stream>>>(dt, xin, proj,
                                                A_log + (size_t)i * 1024 * 16, ys);
        gate_k<<<8000, 256, 0, stream>>>(ys, xin, xz, Dp + i * 1024);
        gemm_f32<false, 0, true><<<gg(2000, 512), blk, 0, stream>>>(
            ys, 1024, W_mo + (size_t)i * 1024 * 512, 512,
            nullptr, h, 512, a, 512, 2000, 512, 1024);
        ln_k<false><<<500, 256, 0, stream>>>(a, ln2_g + i * 512, ln2_b + i * 512, lnb, 2000);
        dcconv31_k<<<4000, 256, 0, stream>>>(lnb, a, dc_w + (size_t)i * 512 * 31,
                                             dc_b + i * 512, h);
    }

    gemm_f32<true, 0, false><<<gg(2000, 514), blk, 0, stream>>>(
        h, 512, w_out, 514, b_out, nullptr, 0, (float*)d_out, 514, 2000, 514, 512);
    mask_k<<<8, 256, 0, stream>>>(lengths, (float*)d_out + 2000 * 514);
}

// Round 2
// 2119.082 us; speedup vs baseline: 1.3224x; 1.3224x over previous
//
#include <hip/hip_runtime.h>
#include <cstdint>
#include <cstddef>

#define DEVI static __device__ __forceinline__

DEVI float sp_softplus(float x) { return x > 20.f ? x : log1pf(__expf(x)); }
DEVI float silu_f(float x)      { return x / (1.f + __expf(-x)); }

#define NC 8
#define CL 125

// ---------------- LayerNorm: one wave per row of 512 ----------------
template<bool RELU>
__global__ __launch_bounds__(256) void ln_k(const float* __restrict__ x,
                                            const float* __restrict__ g,
                                            const float* __restrict__ b,
                                            float* __restrict__ y, int M)
{
    int wid  = threadIdx.x >> 6;
    int lane = threadIdx.x & 63;
    int row  = blockIdx.x * 4 + wid;
    if (row >= M) return;
    const float* xr = x + (size_t)row * 512;
    float4 v0 = *(const float4*)(xr + lane * 8);
    float4 v1 = *(const float4*)(xr + lane * 8 + 4);
    float vals[8] = {v0.x, v0.y, v0.z, v0.w, v1.x, v1.y, v1.z, v1.w};
    float s = 0.f;
#pragma unroll
    for (int i = 0; i < 8; i++) s += vals[i];
#pragma unroll
    for (int off = 1; off < 64; off <<= 1) s += __shfl_xor(s, off);
    float mu = s * (1.f / 512.f);
    float q = 0.f;
#pragma unroll
    for (int i = 0; i < 8; i++) { float d = vals[i] - mu; q += d * d; }
#pragma unroll
    for (int off = 1; off < 64; off <<= 1) q += __shfl_xor(q, off);
    float rstd = rsqrtf(q * (1.f / 512.f) + 1e-5f);
    float* yr = y + (size_t)row * 512;
#pragma unroll
    for (int i = 0; i < 8; i++) {
        int c = lane * 8 + i;
        float o = (vals[i] - mu) * rstd * g[c] + b[c];
        if (RELU) o = fmaxf(o, 0.f);
        yr[c] = o;
    }
}

// ---------------- generic fp32 tiled GEMM: C = A(MxK) @ B(KxN) ----------------
template<bool BIAS, int ACT, bool RES>
__global__ __launch_bounds__(256) void gemm_f32(
    const float* __restrict__ A, int lda,
    const float* __restrict__ B, int ldb,
    const float* __restrict__ bias,
    const float* __restrict__ R, int ldr,
    float* __restrict__ C, int ldc,
    int M, int N, int K)
{
    const int BM = 64, BN = 64, BK = 16;
    __shared__ float As[BK][BM + 4];
    __shared__ float Bs[BK][BN];
    int bm = blockIdx.y * BM, bn = blockIdx.x * BN;
    int tid = threadIdx.x;
    int tx = tid & 15, ty = tid >> 4;
    float acc[4][4] = {};
    for (int k0 = 0; k0 < K; k0 += BK) {
#pragma unroll
        for (int i = 0; i < 4; i++) {
            int lin = tid + i * 256;
            int m = lin >> 4, k = lin & 15;
            int gm = bm + m, gk = k0 + k;
            float v = 0.f;
            if (gm < M && gk < K) v = A[(size_t)gm * lda + gk];
            As[k][m] = v;
        }
#pragma unroll
        for (int i = 0; i < 4; i++) {
            int lin = tid + i * 256;
            int k = lin >> 6, n = lin & 63;
            int gk = k0 + k, gn = bn + n;
            float v = 0.f;
            if (gk < K && gn < N) v = B[(size_t)gk * ldb + gn];
            Bs[k][n] = v;
        }
        __syncthreads();
#pragma unroll
        for (int k = 0; k < BK; k++) {
            float4 av = *(const float4*)&As[k][ty * 4];
            float4 bv = *(const float4*)&Bs[k][tx * 4];
            float ar[4] = {av.x, av.y, av.z, av.w};
            float br[4] = {bv.x, bv.y, bv.z, bv.w};
#pragma unroll
            for (int i = 0; i < 4; i++)
#pragma unroll
                for (int j = 0; j < 4; j++) acc[i][j] += ar[i] * br[j];
        }
        __syncthreads();
    }
#pragma unroll
    for (int i = 0; i < 4; i++) {
        int gm = bm + ty * 4 + i;
        if (gm >= M) continue;
#pragma unroll
        for (int j = 0; j < 4; j++) {
            int gn = bn + tx * 4 + j;
            if (gn >= N) continue;
            float v = acc[i][j];
            if (BIAS) v += bias[gn];
            if (ACT == 1) v = sp_softplus(v);
            if (RES) v += R[(size_t)gm * ldr + gn];
            C[(size_t)gm * ldc + gn] = v;
        }
    }
}

// ---------------- causal depthwise conv (K=4) + SiLU ----------------
__global__ __launch_bounds__(256) void conv4_silu_k(const float* __restrict__ xz,
                                                    const float* __restrict__ w,
                                                    const float* __restrict__ bias,
                                                    float* __restrict__ xin)
{
    int e = blockIdx.x * 256 + threadIdx.x;
    if (e >= 2000 * 1024) return;
    int d = e & 1023;
    int row = e >> 10;
    int b = row >= 1000 ? 1 : 0;
    int t = row - b * 1000;
    float acc = bias[d];
#pragma unroll
    for (int k = 0; k < 4; k++) {
        int tt = t - 3 + k;
        if (tt >= 0) acc += xz[((size_t)(b * 1000 + tt)) * 2048 + d] * w[d * 4 + k];
    }
    xin[(size_t)row * 1024 + d] = silu_f(acc);
}

// ---------------- chunked selective scan ----------------
// part1: per-chunk local end state (h from 0) + per-chunk sum(dt)
__global__ __launch_bounds__(256) void scan_part1(const float* __restrict__ dt,
                                                  const float* __restrict__ xin,
                                                  const float* __restrict__ proj,
                                                  const float* __restrict__ A_log,
                                                  float* __restrict__ hloc,
                                                  float* __restrict__ sc)
{
    __shared__ float s_dt[CL][16], s_x[CL][16], s_B[CL][16];
    int d0 = blockIdx.x * 16;
    int c  = blockIdx.y;
    int b  = blockIdx.z;
    int tid = threadIdx.x;
    int ch = tid >> 4, st = tid & 15;
    int d = d0 + ch;
    float a_s = -__expf(A_log[d * 16 + st]);
    int base = b * 1000 + c * CL;
    for (int lin = tid; lin < CL * 16; lin += 256) {
        int tt = lin >> 4, j = lin & 15;
        size_t row = (size_t)(base + tt);
        s_dt[tt][j] = dt[row * 1024 + d0 + j];
        s_x[tt][j]  = xin[row * 1024 + d0 + j];
        s_B[tt][j]  = proj[row * 64 + 32 + j];
    }
    __syncthreads();
    float h = 0.f, sdt = 0.f;
    for (int t0 = 0; t0 < CL; t0 += 5) {
        float dA[5], du[5];
#pragma unroll
        for (int u = 0; u < 5; u++) {
            float dtv = s_dt[t0 + u][ch];
            dA[u] = __expf(dtv * a_s);
            du[u] = dtv * s_x[t0 + u][ch] * s_B[t0 + u][st];
            sdt += dtv;
        }
#pragma unroll
        for (int u = 0; u < 5; u++) h = dA[u] * h + du[u];
    }
    hloc[((size_t)(b * NC + c) << 14) + ((size_t)d << 4) + st] = h;
    if (st == 0) sc[(b * NC + c) * 1024 + d] = sdt;
}

// combine: sequential over NC chunks; hloc[c] becomes true end-state of chunk c
__global__ __launch_bounds__(256) void scan_combine(const float* __restrict__ A_log,
                                                    float* __restrict__ hloc,
                                                    const float* __restrict__ sc)
{
    int e = blockIdx.x * 256 + threadIdx.x;
    if (e >= 2 * 16384) return;
    int b = e >> 14;
    int rem = e & 16383;
    int dd = rem >> 4;
    float a_s = -__expf(A_log[rem]);
    float H = hloc[((size_t)(b * NC) << 14) + rem];
    for (int c = 1; c < NC; c++) {
        size_t idx = ((size_t)(b * NC + c) << 14) + rem;
        H = hloc[idx] + __expf(a_s * sc[(b * NC + c) * 1024 + dd]) * H;
        hloc[idx] = H;
    }
}

// part2: full scan per chunk starting from true state; writes y
__global__ __launch_bounds__(256) void scan_part2(const float* __restrict__ dt,
                                                  const float* __restrict__ xin,
                                                  const float* __restrict__ proj,
                                                  const float* __restrict__ A_log,
                                                  const float* __restrict__ hend,
                                                  float* __restrict__ ys)
{
    __shared__ float s_dt[CL][16], s_x[CL][16], s_B[CL][16], s_C[CL][16], s_y[CL][16];
    int d0 = blockIdx.x * 16;
    int c  = blockIdx.y;
    int b  = blockIdx.z;
    int tid = threadIdx.x;
    int ch = tid >> 4, st = tid & 15;
    int d = d0 + ch;
    float a_s = -__expf(A_log[d * 16 + st]);
    int base = b * 1000 + c * CL;
    for (int lin = tid; lin < CL * 16; lin += 256) {
        int tt = lin >> 4, j = lin & 15;
        size_t row = (size_t)(base + tt);
        s_dt[tt][j] = dt[row * 1024 + d0 + j];
        s_x[tt][j]  = xin[row * 1024 + d0 + j];
        s_B[tt][j]  = proj[row * 64 + 32 + j];
        s_C[tt][j]  = proj[row * 64 + 48 + j];
    }
    float h = 0.f;
    if (c > 0) h = hend[((size_t)(b * NC + c - 1) << 14) + ((size_t)d << 4) + st];
    __syncthreads();
    for (int t0 = 0; t0 < CL; t0 += 5) {
        float dA[5], du[5], p[5];
#pragma unroll
        for (int u = 0; u < 5; u++) {
            float dtv = s_dt[t0 + u][ch];
            dA[u] = __expf(dtv * a_s);
            du[u] = dtv * s_x[t0 + u][ch] * s_B[t0 + u][st];
        }
#pragma unroll
        for (int u = 0; u < 5; u++) {
            h = dA[u] * h + du[u];
            p[u] = h * s_C[t0 + u][st];
        }
#pragma unroll
        for (int u = 0; u < 5; u++) {
            p[u] += __shfl_xor(p[u], 1);
            p[u] += __shfl_xor(p[u], 2);
            p[u] += __shfl_xor(p[u], 4);
            p[u] += __shfl_xor(p[u], 8);
            if (st == 0) s_y[t0 + u][ch] = p[u];
        }
    }
    __syncthreads();
    for (int lin = tid; lin < CL * 16; lin += 256) {
        int tt = lin >> 4, j = lin & 15;
        ys[(size_t)(base + tt) * 1024 + d0 + j] = s_y[tt][j];
    }
}

// ---------------- gating ----------------
__global__ __launch_bounds__(256) void gate_k(float* __restrict__ ys,
                                              const float* __restrict__ xin,
                                              const float* __restrict__ xz,
                                              const float* __restrict__ Dp)
{
    int e = blockIdx.x * 256 + threadIdx.x;
    if (e >= 2000 * 1024) return;
    int d = e & 1023;
    int row = e >> 10;
    float z = xz[(size_t)row * 2048 + 1024 + d];
    ys[e] = (ys[e] + xin[e] * Dp[d]) * silu_f(z);
}

// ---------------- depthwise conv31 (same pad) + residual add ----------------
__global__ __launch_bounds__(256) void dcconv31_k(const float* __restrict__ ln,
                                                  const float* __restrict__ a,
                                                  const float* __restrict__ w,
                                                  const float* __restrict__ bias,
                                                  float* __restrict__ h)
{
    int e = blockIdx.x * 256 + threadIdx.x;
    if (e >= 2000 * 512) return;
    int m = e & 511;
    int row = e >> 9;
    int b = row >= 1000 ? 1 : 0;
    int t = row - b * 1000;
    float acc = bias[m];
    const float* wr = w + m * 31;
#pragma unroll
    for (int k = 0; k < 31; k++) {
        int tt = t - 15 + k;
        if (tt >= 0 && tt < 1000)
            acc += ln[((size_t)(b * 1000 + tt)) * 512 + m] * wr[k];
    }
    h[e] = a[e] + acc;
}

// ---------------- seq_mask output ----------------
__global__ void mask_k(const int* __restrict__ lengths, float* __restrict__ out)
{
    int i = blockIdx.x * 256 + threadIdx.x;
    if (i >= 2000) return;
    out[i] = ((i % 1000) < lengths[i / 1000]) ? 1.f : 0.f;
}

extern "C" void kernel_launch(void* const* d_in, const int* in_sizes, int n_in,
                              void* d_out, int out_size, void* d_ws, size_t ws_size,
                              hipStream_t stream)
{
    const float* x       = (const float*)d_in[0];
    const int*   lengths = (const int*)  d_in[1];
    const float* w_in0   = (const float*)d_in[2];
    const float* ln_in_g = (const float*)d_in[3];
    const float* ln_in_b = (const float*)d_in[4];
    const float* ln1_g   = (const float*)d_in[5];
    const float* ln1_b   = (const float*)d_in[6];
    const float* W_inproj= (const float*)d_in[7];
    const float* conv_w  = (const float*)d_in[8];
    const float* conv_b  = (const float*)d_in[9];
    const float* W_xproj = (const float*)d_in[10];
    const float* W_dt    = (const float*)d_in[11];
    const float* b_dt    = (const float*)d_in[12];
    const float* A_log   = (const float*)d_in[13];
    const float* Dp      = (const float*)d_in[14];
    const float* W_mo    = (const float*)d_in[15];
    const float* ln2_g   = (const float*)d_in[16];
    const float* ln2_b   = (const float*)d_in[17];
    const float* dc_w    = (const float*)d_in[18];
    const float* dc_b    = (const float*)d_in[19];
    const float* w_out   = (const float*)d_in[20];
    const float* b_out   = (const float*)d_in[21];

    float* ws   = (float*)d_ws;
    float* h    = ws;                 // 2000*512
    float* lnb  = h    + 1024000;     // 2000*512
    float* xz   = lnb  + 1024000;     // 2000*2048
    float* xin  = xz   + 4096000;     // 2000*1024
    float* proj = xin  + 2048000;     // 2000*64
    float* dtb  = proj + 128000;      // 2000*1024
    float* ys   = dtb  + 2048000;     // 2000*1024
    float* a    = ys   + 2048000;     // 2000*512
    float* hloc = a    + 1024000;     // 2*NC*1024*16 = 262144
    float* sc   = hloc + 262144;      // 2*NC*1024 = 16384

    dim3 blk(256);
    auto gg = [](int M, int N) { return dim3((N + 63) / 64, (M + 63) / 64); };

    gemm_f32<false, 0, false><<<gg(2000, 512), blk, 0, stream>>>(
        x, 257, w_in0, 512, nullptr, nullptr, 0, lnb, 512, 2000, 512, 257);
    ln_k<true><<<500, 256, 0, stream>>>(lnb, ln_in_g, ln_in_b, h, 2000);

    for (int i = 0; i < 4; i++) {
        const float* Al = A_log + (size_t)i * 16384;
        ln_k<false><<<500, 256, 0, stream>>>(h, ln1_g + i * 512, ln1_b + i * 512, lnb, 2000);
        gemm_f32<false, 0, false><<<gg(2000, 2048), blk, 0, stream>>>(
            lnb, 512, W_inproj + (size_t)i * 512 * 2048, 2048,
            nullptr, nullptr, 0, xz, 2048, 2000, 2048, 512);
        conv4_silu_k<<<8000, 256, 0, stream>>>(xz, conv_w + (size_t)i * 1024 * 4,
                                               conv_b + i * 1024, xin);
        gemm_f32<false, 0, false><<<gg(2000, 64), blk, 0, stream>>>(
            xin, 1024, W_xproj + (size_t)i * 1024 * 64, 64,
            nullptr, nullptr, 0, proj, 64, 2000, 64, 1024);
        gemm_f32<true, 1, false><<<gg(2000, 1024), blk, 0, stream>>>(
            proj, 64, W_dt + (size_t)i * 32 * 1024, 1024,
            b_dt + i * 1024, nullptr, 0, dtb, 1024, 2000, 1024, 32);
        scan_part1<<<dim3(64, NC, 2), blk, 0, stream>>>(dtb, xin, proj, Al, hloc, sc);
        scan_combine<<<128, blk, 0, stream>>>(Al, hloc, sc);
        scan_part2<<<dim3(64, NC, 2), blk, 0, stream>>>(dtb, xin, proj, Al, hloc, ys);
        gate_k<<<8000, 256, 0, stream>>>(ys, xin, xz, Dp + i * 1024);
        gemm_f32<false, 0, true><<<gg(2000, 512), blk, 0, stream>>>(
            ys, 1024, W_mo + (size_t)i * 1024 * 512, 512,
            nullptr, h, 512, a, 512, 2000, 512, 1024);
        ln_k<false><<<500, 256, 0, stream>>>(a, ln2_g + i * 512, ln2_b + i * 512, lnb, 2000);
        dcconv31_k<<<4000, 256, 0, stream>>>(lnb, a, dc_w + (size_t)i * 512 * 31,
                                             dc_b + i * 512, h);
    }

    gemm_f32<true, 0, false><<<gg(2000, 514), blk, 0, stream>>>(
        h, 512, w_out, 514, b_out, nullptr, 0, (float*)d_out, 514, 2000, 514, 512);
    mask_k<<<8, 256, 0, stream>>>(lengths, (float*)d_out + 2000 * 514);
}

// Round 4
// 868.331 us; speedup vs baseline: 3.2272x; 2.4404x over previous
//
#include <hip/hip_runtime.h>
#include <cstdint>
#include <cstddef>

#define DEVI static __device__ __forceinline__

typedef unsigned short ushort_t;
typedef __attribute__((ext_vector_type(8))) short short8;
typedef __attribute__((ext_vector_type(4))) float f32x4;

DEVI float sp_softplus(float x) { return x > 20.f ? x : log1pf(__expf(x)); }
DEVI float silu_f(float x)      { return x / (1.f + __expf(-x)); }

DEVI ushort_t f2b(float v) {
    uint32_t u = __builtin_bit_cast(uint32_t, v);
    u += 0x7FFFu + ((u >> 16) & 1u);        // round-to-nearest-even
    return (ushort_t)(u >> 16);
}
DEVI float b2f(ushort_t u) {
    uint32_t x = ((uint32_t)u) << 16;
    return __builtin_bit_cast(float, x);
}

DEVI void gload16(const ushort_t* g, ushort_t* l) {
    __builtin_amdgcn_global_load_lds(
        (const __attribute__((address_space(1))) unsigned int*)g,
        (__attribute__((address_space(3))) unsigned int*)l, 16, 0, 0);
}

#define NC 8
#define CL 125

// ---------------- LayerNorm: one wave per row of 512 ----------------
template<bool RELU, bool OUTB16>
__global__ __launch_bounds__(256) void ln_k(const float* __restrict__ x,
                                            const float* __restrict__ g,
                                            const float* __restrict__ b,
                                            void* __restrict__ yv, int M)
{
    int wid  = threadIdx.x >> 6;
    int lane = threadIdx.x & 63;
    int row  = blockIdx.x * 4 + wid;
    if (row >= M) return;
    const float* xr = x + (size_t)row * 512;
    float4 v0 = *(const float4*)(xr + lane * 8);
    float4 v1 = *(const float4*)(xr + lane * 8 + 4);
    float vals[8] = {v0.x, v0.y, v0.z, v0.w, v1.x, v1.y, v1.z, v1.w};
    float s = 0.f;
#pragma unroll
    for (int i = 0; i < 8; i++) s += vals[i];
#pragma unroll
    for (int off = 1; off < 64; off <<= 1) s += __shfl_xor(s, off);
    float mu = s * (1.f / 512.f);
    float q = 0.f;
#pragma unroll
    for (int i = 0; i < 8; i++) { float d = vals[i] - mu; q += d * d; }
#pragma unroll
    for (int off = 1; off < 64; off <<= 1) q += __shfl_xor(q, off);
    float rstd = rsqrtf(q * (1.f / 512.f) + 1e-5f);
#pragma unroll
    for (int i = 0; i < 8; i++) {
        int c = lane * 8 + i;
        float o = (vals[i] - mu) * rstd * g[c] + b[c];
        if (RELU) o = fmaxf(o, 0.f);
        if (OUTB16) ((ushort_t*)yv)[(size_t)row * 512 + c] = f2b(o);
        else        ((float*)yv)[(size_t)row * 512 + c] = o;
    }
}

// ---------------- converters ----------------
__global__ __launch_bounds__(256) void cvt_x_k(const float* __restrict__ x,
                                               ushort_t* __restrict__ xb)
{
    int e = blockIdx.x * 256 + threadIdx.x;
    if (e >= 2000 * 288) return;
    int k = e % 288, row = e / 288;
    xb[e] = (k < 257) ? f2b(x[(size_t)row * 257 + k]) : (ushort_t)0;
}

// transpose+convert: src f32 [K][N] -> dst bf16 [N][ldo], zero-pad k>=Ktrue
__global__ __launch_bounds__(256) void tr_w_k(const float* __restrict__ src,
                                              ushort_t* __restrict__ dst,
                                              int Ktrue, int N, int ldo,
                                              size_t sstride, size_t dstride)
{
    __shared__ float tile[32][33];
    src += blockIdx.z * sstride;
    dst += blockIdx.z * dstride;
    int n0 = blockIdx.x * 32, k0 = blockIdx.y * 32;
    int tx = threadIdx.x & 31, ty = threadIdx.x >> 5;
#pragma unroll
    for (int r = 0; r < 4; r++) {
        int k = k0 + ty + r * 8, n = n0 + tx;
        tile[ty + r * 8][tx] = (k < Ktrue && n < N) ? src[(size_t)k * N + n] : 0.f;
    }
    __syncthreads();
#pragma unroll
    for (int r = 0; r < 4; r++) {
        int n = n0 + ty + r * 8;
        if (n < N) dst[(size_t)n * ldo + k0 + tx] = f2b(tile[tx][ty + r * 8]);
    }
}

// ---------------- bf16 MFMA GEMM ----------------
// A: bf16 [M][lda] (K contiguous). Bt: bf16 [N][ldb] (K contiguous).
template<int BM, int BN, bool BIAS, int ACT, bool RES, bool OUTF32, bool OUTB16>
__global__ __launch_bounds__(256) void gemm_bf16(
    const ushort_t* __restrict__ A, int lda,
    const ushort_t* __restrict__ Bt, int ldb,
    const float* __restrict__ bias,
    const float* __restrict__ R, int ldr,
    float* __restrict__ C, int ldc,
    ushort_t* __restrict__ C2, int ldc2,
    int M, int N, int K)
{
    const int MF = BM / 32, NF = BN / 32;
    __shared__ ushort_t As[4 * BM * 8];
    __shared__ ushort_t Bs[4 * BN * 8];
    int tid = threadIdx.x;
    int wid = tid >> 6, l = tid & 63;
    int wr = wid >> 1, wc = wid & 1;
    int bm = blockIdx.y * BM, bn = blockIdx.x * BN;
    int lk = l >> 4, lr = l & 15;

    f32x4 acc[MF][NF];
#pragma unroll
    for (int m = 0; m < MF; m++)
#pragma unroll
        for (int n = 0; n < NF; n++) acc[m][n] = (f32x4){0.f, 0.f, 0.f, 0.f};

    for (int k0 = 0; k0 < K; k0 += 32) {
#pragma unroll
        for (int i = 0; i < BM / 64; i++) {
            int row = i * 64 + l;
            const ushort_t* g = A + (size_t)(bm + row) * lda + k0 + wid * 8;
            ushort_t* ld = As + ((size_t)wid * BM + i * 64) * 8;
            gload16(g, ld);
        }
#pragma unroll
        for (int i = 0; i < BN / 64; i++) {
            int col = i * 64 + l;
            const ushort_t* g = Bt + (size_t)(bn + col) * ldb + k0 + wid * 8;
            ushort_t* ld = Bs + ((size_t)wid * BN + i * 64) * 8;
            gload16(g, ld);
        }
        asm volatile("s_waitcnt vmcnt(0)" ::: "memory");
        __syncthreads();
        short8 af[MF], bf[NF];
#pragma unroll
        for (int m = 0; m < MF; m++) {
            int row = wr * (BM / 2) + m * 16 + lr;
            af[m] = *(const short8*)&As[((size_t)lk * BM + row) * 8];
        }
#pragma unroll
        for (int n = 0; n < NF; n++) {
            int col = wc * (BN / 2) + n * 16 + lr;
            bf[n] = *(const short8*)&Bs[((size_t)lk * BN + col) * 8];
        }
#pragma unroll
        for (int m = 0; m < MF; m++)
#pragma unroll
            for (int n = 0; n < NF; n++)
                acc[m][n] = __builtin_amdgcn_mfma_f32_16x16x32_bf16(
                    af[m], bf[n], acc[m][n], 0, 0, 0);
        __syncthreads();
    }

    // epilogue: C/D layout col = lane&15, row = (lane>>4)*4 + r
#pragma unroll
    for (int m = 0; m < MF; m++) {
#pragma unroll
        for (int n = 0; n < NF; n++) {
            int gn = bn + wc * (BN / 2) + n * 16 + lr;
            if (gn >= N) continue;
#pragma unroll
            for (int r = 0; r < 4; r++) {
                int gm = bm + wr * (BM / 2) + m * 16 + lk * 4 + r;
                if (gm >= M) continue;
                float v = acc[m][n][r];
                if (BIAS) v += bias[gn];
                if (ACT == 1) v = sp_softplus(v);
                if (RES) v += R[(size_t)gm * ldr + gn];
                if (OUTF32) C[(size_t)gm * ldc + gn] = v;
                if (OUTB16) C2[(size_t)gm * ldc2 + gn] = f2b(v);
            }
        }
    }
}

// ---------------- causal depthwise conv (K=4) + SiLU ----------------
__global__ __launch_bounds__(256) void conv4_silu_k(const ushort_t* __restrict__ xzb,
                                                    const float* __restrict__ w,
                                                    const float* __restrict__ bias,
                                                    float* __restrict__ xin,
                                                    ushort_t* __restrict__ xinb)
{
    int e = blockIdx.x * 256 + threadIdx.x;
    if (e >= 2000 * 1024) return;
    int d = e & 1023;
    int row = e >> 10;
    int b = row >= 1000 ? 1 : 0;
    int t = row - b * 1000;
    float acc = bias[d];
#pragma unroll
    for (int k = 0; k < 4; k++) {
        int tt = t - 3 + k;
        if (tt >= 0) acc += b2f(xzb[((size_t)(b * 1000 + tt)) * 2048 + d]) * w[d * 4 + k];
    }
    float v = silu_f(acc);
    xin[(size_t)row * 1024 + d] = v;
    xinb[(size_t)row * 1024 + d] = f2b(v);
}

// ---------------- chunked selective scan ----------------
__global__ __launch_bounds__(256) void scan_part1(const float* __restrict__ dt,
                                                  const float* __restrict__ xin,
                                                  const float* __restrict__ proj,
                                                  const float* __restrict__ A_log,
                                                  float* __restrict__ hloc,
                                                  float* __restrict__ sc)
{
    __shared__ float s_dt[CL][16], s_x[CL][16], s_B[CL][16];
    int d0 = blockIdx.x * 16;
    int c  = blockIdx.y;
    int b  = blockIdx.z;
    int tid = threadIdx.x;
    int ch = tid >> 4, st = tid & 15;
    int d = d0 + ch;
    float a_s = -__expf(A_log[d * 16 + st]);
    int base = b * 1000 + c * CL;
    for (int lin = tid; lin < CL * 16; lin += 256) {
        int tt = lin >> 4, j = lin & 15;
        size_t row = (size_t)(base + tt);
        s_dt[tt][j] = dt[row * 1024 + d0 + j];
        s_x[tt][j]  = xin[row * 1024 + d0 + j];
        s_B[tt][j]  = proj[row * 64 + 32 + j];
    }
    __syncthreads();
    float h = 0.f, sdt = 0.f;
    for (int t0 = 0; t0 < CL; t0 += 5) {
        float dA[5], du[5];
#pragma unroll
        for (int u = 0; u < 5; u++) {
            float dtv = s_dt[t0 + u][ch];
            dA[u] = __expf(dtv * a_s);
            du[u] = dtv * s_x[t0 + u][ch] * s_B[t0 + u][st];
            sdt += dtv;
        }
#pragma unroll
        for (int u = 0; u < 5; u++) h = dA[u] * h + du[u];
    }
    hloc[((size_t)(b * NC + c) << 14) + ((size_t)d << 4) + st] = h;
    if (st == 0) sc[(b * NC + c) * 1024 + d] = sdt;
}

__global__ __launch_bounds__(256) void scan_combine(const float* __restrict__ A_log,
                                                    float* __restrict__ hloc,
                                                    const float* __restrict__ sc)
{
    int e = blockIdx.x * 256 + threadIdx.x;
    if (e >= 2 * 16384) return;
    int b = e >> 14;
    int rem = e & 16383;
    int dd = rem >> 4;
    float a_s = -__expf(A_log[rem]);
    float H = hloc[((size_t)(b * NC) << 14) + rem];
    for (int c = 1; c < NC; c++) {
        size_t idx = ((size_t)(b * NC + c) << 14) + rem;
        H = hloc[idx] + __expf(a_s * sc[(b * NC + c) * 1024 + dd]) * H;
        hloc[idx] = H;
    }
}

__global__ __launch_bounds__(256) void scan_part2(const float* __restrict__ dt,
                                                  const float* __restrict__ xin,
                                                  const float* __restrict__ proj,
                                                  const float* __restrict__ A_log,
                                                  const float* __restrict__ hend,
                                                  float* __restrict__ ys)
{
    __shared__ float s_dt[CL][16], s_x[CL][16], s_B[CL][16], s_C[CL][16], s_y[CL][16];
    int d0 = blockIdx.x * 16;
    int c  = blockIdx.y;
    int b  = blockIdx.z;
    int tid = threadIdx.x;
    int ch = tid >> 4, st = tid & 15;
    int d = d0 + ch;
    float a_s = -__expf(A_log[d * 16 + st]);
    int base = b * 1000 + c * CL;
    for (int lin = tid; lin < CL * 16; lin += 256) {
        int tt = lin >> 4, j = lin & 15;
        size_t row = (size_t)(base + tt);
        s_dt[tt][j] = dt[row * 1024 + d0 + j];
        s_x[tt][j]  = xin[row * 1024 + d0 + j];
        s_B[tt][j]  = proj[row * 64 + 32 + j];
        s_C[tt][j]  = proj[row * 64 + 48 + j];
    }
    float h = 0.f;
    if (c > 0) h = hend[((size_t)(b * NC + c - 1) << 14) + ((size_t)d << 4) + st];
    __syncthreads();
    for (int t0 = 0; t0 < CL; t0 += 5) {
        float dA[5], du[5], p[5];
#pragma unroll
        for (int u = 0; u < 5; u++) {
            float dtv = s_dt[t0 + u][ch];
            dA[u] = __expf(dtv * a_s);
            du[u] = dtv * s_x[t0 + u][ch] * s_B[t0 + u][st];
        }
#pragma unroll
        for (int u = 0; u < 5; u++) {
            h = dA[u] * h + du[u];
            p[u] = h * s_C[t0 + u][st];
        }
#pragma unroll
        for (int u = 0; u < 5; u++) {
            p[u] += __shfl_xor(p[u], 1);
            p[u] += __shfl_xor(p[u], 2);
            p[u] += __shfl_xor(p[u], 4);
            p[u] += __shfl_xor(p[u], 8);
            if (st == 0) s_y[t0 + u][ch] = p[u];
        }
    }
    __syncthreads();
    for (int lin = tid; lin < CL * 16; lin += 256) {
        int tt = lin >> 4, j = lin & 15;
        ys[(size_t)(base + tt) * 1024 + d0 + j] = s_y[tt][j];
    }
}

// ---------------- gating ----------------
__global__ __launch_bounds__(256) void gate_k(const float* __restrict__ ys,
                                              const float* __restrict__ xin,
                                              const ushort_t* __restrict__ xzb,
                                              const float* __restrict__ Dp,
                                              ushort_t* __restrict__ ysb)
{
    int e = blockIdx.x * 256 + threadIdx.x;
    if (e >= 2000 * 1024) return;
    int d = e & 1023;
    int row = e >> 10;
    float z = b2f(xzb[(size_t)row * 2048 + 1024 + d]);
    ysb[e] = f2b((ys[e] + xin[e] * Dp[d]) * silu_f(z));
}

// ---------------- depthwise conv31 + residual ----------------
__global__ __launch_bounds__(256) void dcconv31_k(const float* __restrict__ ln,
                                                  const float* __restrict__ a,
                                                  const float* __restrict__ w,
                                                  const float* __restrict__ bias,
                                                  float* __restrict__ h,
                                                  ushort_t* __restrict__ hb)
{
    int e = blockIdx.x * 256 + threadIdx.x;
    if (e >= 2000 * 512) return;
    int m = e & 511;
    int row = e >> 9;
    int b = row >= 1000 ? 1 : 0;
    int t = row - b * 1000;
    float acc = bias[m];
    const float* wr = w + m * 31;
#pragma unroll
    for (int k = 0; k < 31; k++) {
        int tt = t - 15 + k;
        if (tt >= 0 && tt < 1000)
            acc += ln[((size_t)(b * 1000 + tt)) * 512 + m] * wr[k];
    }
    float v = a[e] + acc;
    h[e] = v;
    hb[e] = f2b(v);
}

// ---------------- seq_mask output ----------------
__global__ void mask_k(const int* __restrict__ lengths, float* __restrict__ out)
{
    int i = blockIdx.x * 256 + threadIdx.x;
    if (i >= 2000) return;
    out[i] = ((i % 1000) < lengths[i / 1000]) ? 1.f : 0.f;
}

extern "C" void kernel_launch(void* const* d_in, const int* in_sizes, int n_in,
                              void* d_out, int out_size, void* d_ws, size_t ws_size,
                              hipStream_t stream)
{
    const float* x       = (const float*)d_in[0];
    const int*   lengths = (const int*)  d_in[1];
    const float* w_in0   = (const float*)d_in[2];
    const float* ln_in_g = (const float*)d_in[3];
    const float* ln_in_b = (const float*)d_in[4];
    const float* ln1_g   = (const float*)d_in[5];
    const float* ln1_b   = (const float*)d_in[6];
    const float* W_inproj= (const float*)d_in[7];
    const float* conv_w  = (const float*)d_in[8];
    const float* conv_b  = (const float*)d_in[9];
    const float* W_xproj = (const float*)d_in[10];
    const float* W_dt    = (const float*)d_in[11];
    const float* b_dt    = (const float*)d_in[12];
    const float* A_log   = (const float*)d_in[13];
    const float* Dp      = (const float*)d_in[14];
    const float* W_mo    = (const float*)d_in[15];
    const float* ln2_g   = (const float*)d_in[16];
    const float* ln2_b   = (const float*)d_in[17];
    const float* dc_w    = (const float*)d_in[18];
    const float* dc_b    = (const float*)d_in[19];
    const float* w_out   = (const float*)d_in[20];
    const float* b_out   = (const float*)d_in[21];

    char* p = (char*)d_ws;
    auto alloc_f = [&](size_t n) { float* r = (float*)p; p += n * 4; return r; };
    auto alloc_b = [&](size_t n) { ushort_t* r = (ushort_t*)p; p += n * 2; return r; };

    float* h    = alloc_f(2048 * 512);
    float* lnb  = alloc_f(2048 * 512);
    float* xin  = alloc_f(2048 * 1024);
    float* proj = alloc_f(2048 * 64);
    float* dtb  = alloc_f(2048 * 1024);
    float* ys   = alloc_f(2048 * 1024);
    float* av   = alloc_f(2048 * 512);
    float* hloc = alloc_f(262144);
    float* sc   = alloc_f(16384);
    ushort_t* xbf   = alloc_b(2048 * 288);
    ushort_t* lnbb  = alloc_b(2048 * 512);
    ushort_t* xzb   = alloc_b(2048 * 2048);
    ushort_t* xinb  = alloc_b(2048 * 1024);
    ushort_t* projb = alloc_b(2048 * 64);
    ushort_t* ysb   = alloc_b(2048 * 1024);
    ushort_t* hb    = alloc_b(2048 * 512);
    ushort_t* wt_in0 = alloc_b(512 * 288);
    ushort_t* wt_in  = alloc_b((size_t)4 * 2048 * 512);
    ushort_t* wt_x   = alloc_b((size_t)4 * 64 * 1024);
    ushort_t* wt_dt  = alloc_b((size_t)4 * 1024 * 32);
    ushort_t* wt_mo  = alloc_b((size_t)4 * 512 * 1024);
    ushort_t* wt_out = alloc_b(576 * 512);

    dim3 blk(256);

    cvt_x_k<<<(2000 * 288 + 255) / 256, blk, 0, stream>>>(x, xbf);
    tr_w_k<<<dim3(16, 9, 1),  blk, 0, stream>>>(w_in0, wt_in0, 257, 512, 288, 0, 0);
    tr_w_k<<<dim3(64, 16, 4), blk, 0, stream>>>(W_inproj, wt_in, 512, 2048, 512,
                                                (size_t)512 * 2048, (size_t)2048 * 512);
    tr_w_k<<<dim3(2, 32, 4),  blk, 0, stream>>>(W_xproj, wt_x, 1024, 64, 1024,
                                                (size_t)1024 * 64, (size_t)64 * 1024);
    tr_w_k<<<dim3(32, 1, 4),  blk, 0, stream>>>(W_dt, wt_dt, 32, 1024, 32,
                                                (size_t)32 * 1024, (size_t)1024 * 32);
    tr_w_k<<<dim3(16, 32, 4), blk, 0, stream>>>(W_mo, wt_mo, 1024, 512, 1024,
                                                (size_t)1024 * 512, (size_t)512 * 1024);
    tr_w_k<<<dim3(17, 16, 1), blk, 0, stream>>>(w_out, wt_out, 512, 514, 512, 0, 0);

    gemm_bf16<64, 64, false, 0, false, true, false><<<dim3(8, 32), blk, 0, stream>>>(
        xbf, 288, wt_in0, 288, nullptr, nullptr, 0, lnb, 512, nullptr, 0, 2000, 512, 288);
    ln_k<true, false><<<500, blk, 0, stream>>>(lnb, ln_in_g, ln_in_b, h, 2000);

    for (int i = 0; i < 4; i++) {
        const float* Al = A_log + (size_t)i * 16384;
        ln_k<false, true><<<500, blk, 0, stream>>>(h, ln1_g + i * 512, ln1_b + i * 512,
                                                   lnbb, 2000);
        gemm_bf16<64, 128, false, 0, false, false, true><<<dim3(16, 32), blk, 0, stream>>>(
            lnbb, 512, wt_in + (size_t)i * 2048 * 512, 512,
            nullptr, nullptr, 0, nullptr, 0, xzb, 2048, 2000, 2048, 512);
        conv4_silu_k<<<8000, blk, 0, stream>>>(xzb, conv_w + (size_t)i * 4096,
                                               conv_b + i * 1024, xin, xinb);
        gemm_bf16<64, 64, false, 0, false, true, true><<<dim3(1, 32), blk, 0, stream>>>(
            xinb, 1024, wt_x + (size_t)i * 64 * 1024, 1024,
            nullptr, nullptr, 0, proj, 64, projb, 64, 2000, 64, 1024);
        gemm_bf16<64, 64, true, 1, false, true, false><<<dim3(16, 32), blk, 0, stream>>>(
            projb, 64, wt_dt + (size_t)i * 1024 * 32, 32,
            b_dt + i * 1024, nullptr, 0, dtb, 1024, nullptr, 0, 2000, 1024, 32);
        scan_part1<<<dim3(64, NC, 2), blk, 0, stream>>>(dtb, xin, proj, Al, hloc, sc);
        scan_combine<<<128, blk, 0, stream>>>(Al, hloc, sc);
        scan_part2<<<dim3(64, NC, 2), blk, 0, stream>>>(dtb, xin, proj, Al, hloc, ys);
        gate_k<<<8000, blk, 0, stream>>>(ys, xin, xzb, Dp + i * 1024, ysb);
        gemm_bf16<64, 64, false, 0, true, true, false><<<dim3(8, 32), blk, 0, stream>>>(
            ysb, 1024, wt_mo + (size_t)i * 512 * 1024, 1024,
            nullptr, h, 512, av, 512, nullptr, 0, 2000, 512, 1024);
        ln_k<false, false><<<500, blk, 0, stream>>>(av, ln2_g + i * 512, ln2_b + i * 512,
                                                    lnb, 2000);
        dcconv31_k<<<4000, blk, 0, stream>>>(lnb, av, dc_w + (size_t)i * 512 * 31,
                                             dc_b + i * 512, h, hb);
    }

    gemm_bf16<64, 64, true, 0, false, true, false><<<dim3(9, 32), blk, 0, stream>>>(
        hb, 512, wt_out, 512, b_out, nullptr, 0, (float*)d_out, 514, nullptr, 0,
        2000, 514, 512);
    mask_k<<<8, blk, 0, stream>>>(lengths, (float*)d_out + 2000 * 514);
}

// Round 5
// 760.565 us; speedup vs baseline: 3.6845x; 1.1417x over previous
//
#include <hip/hip_runtime.h>
#include <cstdint>
#include <cstddef>

#define DEVI static __device__ __forceinline__

typedef unsigned short ushort_t;
typedef __attribute__((ext_vector_type(8))) short short8;
typedef __attribute__((ext_vector_type(4))) float f32x4;

DEVI float sp_softplus(float x) { return x > 20.f ? x : log1pf(__expf(x)); }
DEVI float silu_f(float x)      { return x / (1.f + __expf(-x)); }

DEVI ushort_t f2b(float v) {
    uint32_t u = __builtin_bit_cast(uint32_t, v);
    u += 0x7FFFu + ((u >> 16) & 1u);
    return (ushort_t)(u >> 16);
}
DEVI float b2f(ushort_t u) {
    uint32_t x = ((uint32_t)u) << 16;
    return __builtin_bit_cast(float, x);
}

DEVI void gload16(const ushort_t* g, ushort_t* l) {
    __builtin_amdgcn_global_load_lds(
        (const __attribute__((address_space(1))) unsigned int*)g,
        (__attribute__((address_space(3))) unsigned int*)l, 16, 0, 0);
}

#define NC 8
#define CL 125

// ---------------- LayerNorm: one wave per row of 512 ----------------
template<bool RELU, bool OUTB16>
__global__ __launch_bounds__(256) void ln_k(const float* __restrict__ x,
                                            const float* __restrict__ g,
                                            const float* __restrict__ b,
                                            void* __restrict__ yv, int M)
{
    int wid  = threadIdx.x >> 6;
    int lane = threadIdx.x & 63;
    int row  = blockIdx.x * 4 + wid;
    if (row >= M) return;
    const float* xr = x + (size_t)row * 512;
    float4 v0 = *(const float4*)(xr + lane * 8);
    float4 v1 = *(const float4*)(xr + lane * 8 + 4);
    float vals[8] = {v0.x, v0.y, v0.z, v0.w, v1.x, v1.y, v1.z, v1.w};
    float s = 0.f;
#pragma unroll
    for (int i = 0; i < 8; i++) s += vals[i];
#pragma unroll
    for (int off = 1; off < 64; off <<= 1) s += __shfl_xor(s, off);
    float mu = s * (1.f / 512.f);
    float q = 0.f;
#pragma unroll
    for (int i = 0; i < 8; i++) { float d = vals[i] - mu; q += d * d; }
#pragma unroll
    for (int off = 1; off < 64; off <<= 1) q += __shfl_xor(q, off);
    float rstd = rsqrtf(q * (1.f / 512.f) + 1e-5f);
#pragma unroll
    for (int i = 0; i < 8; i++) {
        int c = lane * 8 + i;
        float o = (vals[i] - mu) * rstd * g[c] + b[c];
        if (RELU) o = fmaxf(o, 0.f);
        if (OUTB16) ((ushort_t*)yv)[(size_t)row * 512 + c] = f2b(o);
        else        ((float*)yv)[(size_t)row * 512 + c] = o;
    }
}

// ---------------- converters ----------------
__global__ __launch_bounds__(256) void cvt_x_k(const float* __restrict__ x,
                                               ushort_t* __restrict__ xb)
{
    int e = blockIdx.x * 256 + threadIdx.x;
    if (e >= 2000 * 288) return;
    int k = e % 288, row = e / 288;
    xb[e] = (k < 257) ? f2b(x[(size_t)row * 257 + k]) : (ushort_t)0;
}

// small weight reshapes: conv4 w -> [4][1024], dc w -> [31][512], W_xproj -> bf16
__global__ __launch_bounds__(256) void prep_small_k(const float* __restrict__ conv_w,
                                                    const float* __restrict__ dc_w,
                                                    const float* __restrict__ W_xproj,
                                                    float* __restrict__ cwt,
                                                    float* __restrict__ dcwt,
                                                    ushort_t* __restrict__ wxb)
{
    int e = blockIdx.x * 256 + threadIdx.x;
    if (e < 16384) {
        int l = e >> 12, rem = e & 4095, k = rem >> 10, d = rem & 1023;
        cwt[e] = conv_w[l * 4096 + d * 4 + k];
        return;
    }
    e -= 16384;
    if (e < 63488) {
        int l = e / 15872, rem = e % 15872, k = rem / 512, m = rem % 512;
        dcwt[e] = dc_w[l * 15872 + m * 31 + k];
        return;
    }
    e -= 63488;
    if (e < 262144) wxb[e] = f2b(W_xproj[e]);
}

// transpose+convert: src f32 [K][N] (ld srcld) -> dst bf16 [N][ldo], zero-pad k>=Ktrue
__global__ __launch_bounds__(256) void tr_w_k(const float* __restrict__ src,
                                              ushort_t* __restrict__ dst,
                                              int Ktrue, int N, int ldo, int srcld,
                                              size_t sstride, size_t dstride)
{
    __shared__ float tile[32][33];
    src += blockIdx.z * sstride;
    dst += blockIdx.z * dstride;
    int n0 = blockIdx.x * 32, k0 = blockIdx.y * 32;
    int tx = threadIdx.x & 31, ty = threadIdx.x >> 5;
#pragma unroll
    for (int r = 0; r < 4; r++) {
        int k = k0 + ty + r * 8, n = n0 + tx;
        tile[ty + r * 8][tx] = (k < Ktrue && n < N) ? src[(size_t)k * srcld + n] : 0.f;
    }
    __syncthreads();
#pragma unroll
    for (int r = 0; r < 4; r++) {
        int n = n0 + ty + r * 8;
        if (n < N) dst[(size_t)n * ldo + k0 + tx] = f2b(tile[tx][ty + r * 8]);
    }
}

// ---------------- bf16 MFMA GEMM ----------------
// A: bf16 [M][lda] (K contiguous). Bt: bf16 [N][ldb] (K contiguous).
// ACT: 0 none, 1 softplus(+bias), 2 split dt/proj (dt=softplus(v+bias) to C f32 ld 1024;
//      cols >=1024 raw to R(f32, ld 64) at +32)
template<int BM, int BN, bool BIAS, int ACT, bool RES, bool OUTF32, bool OUTB16>
__global__ __launch_bounds__(256) void gemm_bf16(
    const ushort_t* __restrict__ A, int lda,
    const ushort_t* __restrict__ Bt, int ldb,
    const float* __restrict__ bias,
    const float* __restrict__ R, int ldr,
    float* __restrict__ C, int ldc,
    ushort_t* __restrict__ C2, int ldc2,
    int M, int N, int K)
{
    const int MF = BM / 32, NF = BN / 32;
    __shared__ ushort_t As[4 * BM * 8];
    __shared__ ushort_t Bs[4 * BN * 8];
    int tid = threadIdx.x;
    int wid = tid >> 6, l = tid & 63;
    int wr = wid >> 1, wc = wid & 1;
    int bm = blockIdx.y * BM, bn = blockIdx.x * BN;
    int lk = l >> 4, lr = l & 15;

    f32x4 acc[MF][NF];
#pragma unroll
    for (int m = 0; m < MF; m++)
#pragma unroll
        for (int n = 0; n < NF; n++) acc[m][n] = (f32x4){0.f, 0.f, 0.f, 0.f};

    for (int k0 = 0; k0 < K; k0 += 32) {
#pragma unroll
        for (int i = 0; i < BM / 64; i++) {
            int row = i * 64 + l;
            const ushort_t* g = A + (size_t)(bm + row) * lda + k0 + wid * 8;
            ushort_t* ld = As + ((size_t)wid * BM + i * 64) * 8;
            gload16(g, ld);
        }
#pragma unroll
        for (int i = 0; i < BN / 64; i++) {
            int col = i * 64 + l;
            const ushort_t* g = Bt + (size_t)(bn + col) * ldb + k0 + wid * 8;
            ushort_t* ld = Bs + ((size_t)wid * BN + i * 64) * 8;
            gload16(g, ld);
        }
        asm volatile("s_waitcnt vmcnt(0)" ::: "memory");
        __syncthreads();
        short8 af[MF], bf[NF];
#pragma unroll
        for (int m = 0; m < MF; m++) {
            int row = wr * (BM / 2) + m * 16 + lr;
            af[m] = *(const short8*)&As[((size_t)lk * BM + row) * 8];
        }
#pragma unroll
        for (int n = 0; n < NF; n++) {
            int col = wc * (BN / 2) + n * 16 + lr;
            bf[n] = *(const short8*)&Bs[((size_t)lk * BN + col) * 8];
        }
#pragma unroll
        for (int m = 0; m < MF; m++)
#pragma unroll
            for (int n = 0; n < NF; n++)
                acc[m][n] = __builtin_amdgcn_mfma_f32_16x16x32_bf16(
                    af[m], bf[n], acc[m][n], 0, 0, 0);
        __syncthreads();
    }

    // epilogue: C/D layout col = lane&15, row = (lane>>4)*4 + r
#pragma unroll
    for (int m = 0; m < MF; m++) {
#pragma unroll
        for (int n = 0; n < NF; n++) {
            int gn = bn + wc * (BN / 2) + n * 16 + lr;
            if (gn >= N) continue;
#pragma unroll
            for (int r = 0; r < 4; r++) {
                int gm = bm + wr * (BM / 2) + m * 16 + lk * 4 + r;
                if (gm >= M) continue;
                float v = acc[m][n][r];
                if (ACT == 2) {
                    if (gn < 1024) C[(size_t)gm * ldc + gn] = sp_softplus(v + bias[gn]);
                    else ((float*)R)[(size_t)gm * ldr + (gn - 1024) + 32] = v;
                    continue;
                }
                if (BIAS) v += bias[gn];
                if (ACT == 1) v = sp_softplus(v);
                if (RES) v += R[(size_t)gm * ldr + gn];
                if (OUTF32) C[(size_t)gm * ldc + gn] = v;
                if (OUTB16) C2[(size_t)gm * ldc2 + gn] = f2b(v);
            }
        }
    }
}

// ---------------- causal depthwise conv (K=4) + SiLU ----------------
__global__ __launch_bounds__(256) void conv4_silu_k(const ushort_t* __restrict__ xzb,
                                                    const float* __restrict__ cwt,
                                                    const float* __restrict__ bias,
                                                    float* __restrict__ xin,
                                                    ushort_t* __restrict__ xinb)
{
    int e = blockIdx.x * 256 + threadIdx.x;
    if (e >= 2000 * 1024) return;
    int d = e & 1023;
    int row = e >> 10;
    int b = row >= 1000 ? 1 : 0;
    int t = row - b * 1000;
    float acc = bias[d];
#pragma unroll
    for (int k = 0; k < 4; k++) {
        int tt = t - 3 + k;
        if (tt >= 0) acc += b2f(xzb[((size_t)(b * 1000 + tt)) * 2048 + d]) * cwt[k * 1024 + d];
    }
    float v = silu_f(acc);
    xin[(size_t)row * 1024 + d] = v;
    xinb[(size_t)row * 1024 + d] = f2b(v);
}

// ---------------- chunked selective scan ----------------
__global__ __launch_bounds__(256) void scan_part1(const float* __restrict__ dt,
                                                  const float* __restrict__ xin,
                                                  const float* __restrict__ proj,
                                                  const float* __restrict__ A_log,
                                                  float* __restrict__ hloc,
                                                  float* __restrict__ sc)
{
    __shared__ float s_dt[CL][16], s_x[CL][16], s_B[CL][16];
    int d0 = blockIdx.x * 16;
    int c  = blockIdx.y;
    int b  = blockIdx.z;
    int tid = threadIdx.x;
    int ch = tid >> 4, st = tid & 15;
    int d = d0 + ch;
    float a_s = -__expf(A_log[d * 16 + st]);
    int base = b * 1000 + c * CL;
    for (int lin = tid; lin < CL * 16; lin += 256) {
        int tt = lin >> 4, j = lin & 15;
        size_t row = (size_t)(base + tt);
        s_dt[tt][j] = dt[row * 1024 + d0 + j];
        s_x[tt][j]  = xin[row * 1024 + d0 + j];
        s_B[tt][j]  = proj[row * 64 + 32 + j];
    }
    __syncthreads();
    float h = 0.f, sdt = 0.f;
    for (int t0 = 0; t0 < CL; t0 += 5) {
        float dA[5], du[5];
#pragma unroll
        for (int u = 0; u < 5; u++) {
            float dtv = s_dt[t0 + u][ch];
            dA[u] = __expf(dtv * a_s);
            du[u] = dtv * s_x[t0 + u][ch] * s_B[t0 + u][st];
            sdt += dtv;
        }
#pragma unroll
        for (int u = 0; u < 5; u++) h = dA[u] * h + du[u];
    }
    hloc[((size_t)(b * NC + c) << 14) + ((size_t)d << 4) + st] = h;
    if (st == 0) sc[(b * NC + c) * 1024 + d] = sdt;
}

__global__ __launch_bounds__(256) void scan_combine(const float* __restrict__ A_log,
                                                    float* __restrict__ hloc,
                                                    const float* __restrict__ sc)
{
    int e = blockIdx.x * 256 + threadIdx.x;
    if (e >= 2 * 16384) return;
    int b = e >> 14;
    int rem = e & 16383;
    int dd = rem >> 4;
    float a_s = -__expf(A_log[rem]);
    float H = hloc[((size_t)(b * NC) << 14) + rem];
    for (int c = 1; c < NC; c++) {
        size_t idx = ((size_t)(b * NC + c) << 14) + rem;
        H = hloc[idx] + __expf(a_s * sc[(b * NC + c) * 1024 + dd]) * H;
        hloc[idx] = H;
    }
}

// part2 + fused gating: writes ysb = bf16((y + xin*Dp) * silu(z))
__global__ __launch_bounds__(256) void scan_part2(const float* __restrict__ dt,
                                                  const float* __restrict__ xin,
                                                  const float* __restrict__ proj,
                                                  const float* __restrict__ A_log,
                                                  const float* __restrict__ hend,
                                                  const float* __restrict__ Dp,
                                                  const ushort_t* __restrict__ xzb,
                                                  ushort_t* __restrict__ ysb)
{
    __shared__ float s_dt[CL][16], s_x[CL][16], s_B[CL][16], s_C[CL][16], s_y[CL][16];
    int d0 = blockIdx.x * 16;
    int c  = blockIdx.y;
    int b  = blockIdx.z;
    int tid = threadIdx.x;
    int ch = tid >> 4, st = tid & 15;
    int d = d0 + ch;
    float a_s = -__expf(A_log[d * 16 + st]);
    int base = b * 1000 + c * CL;
    for (int lin = tid; lin < CL * 16; lin += 256) {
        int tt = lin >> 4, j = lin & 15;
        size_t row = (size_t)(base + tt);
        s_dt[tt][j] = dt[row * 1024 + d0 + j];
        s_x[tt][j]  = xin[row * 1024 + d0 + j];
        s_B[tt][j]  = proj[row * 64 + 32 + j];
        s_C[tt][j]  = proj[row * 64 + 48 + j];
    }
    float h = 0.f;
    if (c > 0) h = hend[((size_t)(b * NC + c - 1) << 14) + ((size_t)d << 4) + st];
    __syncthreads();
    for (int t0 = 0; t0 < CL; t0 += 5) {
        float dA[5], du[5], p[5];
#pragma unroll
        for (int u = 0; u < 5; u++) {
            float dtv = s_dt[t0 + u][ch];
            dA[u] = __expf(dtv * a_s);
            du[u] = dtv * s_x[t0 + u][ch] * s_B[t0 + u][st];
        }
#pragma unroll
        for (int u = 0; u < 5; u++) {
            h = dA[u] * h + du[u];
            p[u] = h * s_C[t0 + u][st];
        }
#pragma unroll
        for (int u = 0; u < 5; u++) {
            p[u] += __shfl_xor(p[u], 1);
            p[u] += __shfl_xor(p[u], 2);
            p[u] += __shfl_xor(p[u], 4);
            p[u] += __shfl_xor(p[u], 8);
            if (st == 0) s_y[t0 + u][ch] = p[u];
        }
    }
    __syncthreads();
    for (int lin = tid; lin < CL * 16; lin += 256) {
        int tt = lin >> 4, j = lin & 15;
        size_t row = (size_t)(base + tt);
        float z = b2f(xzb[row * 2048 + 1024 + d0 + j]);
        float yv = (s_y[tt][j] + s_x[tt][j] * Dp[d0 + j]) * silu_f(z);
        ysb[row * 1024 + d0 + j] = f2b(yv);
    }
}

// ---------------- depthwise conv31 + residual (coalesced weights) ----------------
__global__ __launch_bounds__(256) void dcconv31_k(const float* __restrict__ ln,
                                                  const float* __restrict__ a,
                                                  const float* __restrict__ dcwt,
                                                  const float* __restrict__ bias,
                                                  float* __restrict__ h,
                                                  ushort_t* __restrict__ hb)
{
    int e = blockIdx.x * 256 + threadIdx.x;
    if (e >= 2000 * 512) return;
    int m = e & 511;
    int row = e >> 9;
    int b = row >= 1000 ? 1 : 0;
    int t = row - b * 1000;
    float acc = bias[m];
#pragma unroll
    for (int k = 0; k < 31; k++) {
        int tt = t - 15 + k;
        if (tt >= 0 && tt < 1000)
            acc += ln[((size_t)(b * 1000 + tt)) * 512 + m] * dcwt[k * 512 + m];
    }
    float v = a[e] + acc;
    h[e] = v;
    hb[e] = f2b(v);
}

// ---------------- seq_mask output ----------------
__global__ void mask_k(const int* __restrict__ lengths, float* __restrict__ out)
{
    int i = blockIdx.x * 256 + threadIdx.x;
    if (i >= 2000) return;
    out[i] = ((i % 1000) < lengths[i / 1000]) ? 1.f : 0.f;
}

extern "C" void kernel_launch(void* const* d_in, const int* in_sizes, int n_in,
                              void* d_out, int out_size, void* d_ws, size_t ws_size,
                              hipStream_t stream)
{
    const float* x       = (const float*)d_in[0];
    const int*   lengths = (const int*)  d_in[1];
    const float* w_in0   = (const float*)d_in[2];
    const float* ln_in_g = (const float*)d_in[3];
    const float* ln_in_b = (const float*)d_in[4];
    const float* ln1_g   = (const float*)d_in[5];
    const float* ln1_b   = (const float*)d_in[6];
    const float* W_inproj= (const float*)d_in[7];
    const float* conv_w  = (const float*)d_in[8];
    const float* conv_b  = (const float*)d_in[9];
    const float* W_xproj = (const float*)d_in[10];
    const float* W_dt    = (const float*)d_in[11];
    const float* b_dt    = (const float*)d_in[12];
    const float* A_log   = (const float*)d_in[13];
    const float* Dp      = (const float*)d_in[14];
    const float* W_mo    = (const float*)d_in[15];
    const float* ln2_g   = (const float*)d_in[16];
    const float* ln2_b   = (const float*)d_in[17];
    const float* dc_w    = (const float*)d_in[18];
    const float* dc_b    = (const float*)d_in[19];
    const float* w_out   = (const float*)d_in[20];
    const float* b_out   = (const float*)d_in[21];

    char* p = (char*)d_ws;
    auto alloc_f = [&](size_t n) { float* r = (float*)p; p += n * 4; return r; };
    auto alloc_b = [&](size_t n) { ushort_t* r = (ushort_t*)p; p += n * 2; return r; };

    float* h    = alloc_f(2048 * 512);
    float* lnb  = alloc_f(2048 * 512);
    float* xin  = alloc_f(2048 * 1024);
    float* proj = alloc_f(2048 * 64);
    float* dtb  = alloc_f(2048 * 1024);
    float* av   = alloc_f(2048 * 512);
    float* hloc = alloc_f(262144);
    float* sc   = alloc_f(16384);
    float* cwt  = alloc_f(4 * 4 * 1024);
    float* dcwt = alloc_f(4 * 31 * 512);
    ushort_t* xbf   = alloc_b(2048 * 288);
    ushort_t* lnbb  = alloc_b(2048 * 512);
    ushort_t* xzb   = alloc_b(2048 * 2048);
    ushort_t* xinb  = alloc_b(2048 * 1024);
    ushort_t* ysb   = alloc_b(2048 * 1024);
    ushort_t* hb    = alloc_b(2048 * 512);
    ushort_t* wt_in0 = alloc_b(512 * 288);
    ushort_t* wt_in  = alloc_b((size_t)4 * 2048 * 512);
    ushort_t* wt_dt  = alloc_b((size_t)4 * 1024 * 32);
    ushort_t* wt_mo  = alloc_b((size_t)4 * 512 * 1024);
    ushort_t* wt_out = alloc_b(576 * 512);
    ushort_t* wxb    = alloc_b((size_t)4 * 1024 * 64);
    ushort_t* wt_big = alloc_b((size_t)4 * 1088 * 1024);

    dim3 blk(256);

    // ---- weight prep ----
    cvt_x_k<<<(2000 * 288 + 255) / 256, blk, 0, stream>>>(x, xbf);
    prep_small_k<<<(16384 + 63488 + 262144 + 255) / 256, blk, 0, stream>>>(
        conv_w, dc_w, W_xproj, cwt, dcwt, wxb);
    tr_w_k<<<dim3(16, 9, 1),  blk, 0, stream>>>(w_in0, wt_in0, 257, 512, 288, 512, 0, 0);
    tr_w_k<<<dim3(64, 16, 4), blk, 0, stream>>>(W_inproj, wt_in, 512, 2048, 512, 2048,
                                                (size_t)512 * 2048, (size_t)2048 * 512);
    tr_w_k<<<dim3(32, 1, 4),  blk, 0, stream>>>(W_dt, wt_dt, 32, 1024, 32, 1024,
                                                (size_t)32 * 1024, (size_t)1024 * 32);
    tr_w_k<<<dim3(16, 32, 4), blk, 0, stream>>>(W_mo, wt_mo, 1024, 512, 1024, 512,
                                                (size_t)1024 * 512, (size_t)512 * 1024);
    tr_w_k<<<dim3(17, 16, 1), blk, 0, stream>>>(w_out, wt_out, 512, 514, 512, 514, 0, 0);
    // W_x[:,32:64] transposed into wt_big rows 1024..1055
    tr_w_k<<<dim3(1, 32, 4),  blk, 0, stream>>>(W_xproj + 32, wt_big + (size_t)1024 * 1024,
                                                1024, 32, 1024, 64,
                                                (size_t)1024 * 64, (size_t)1088 * 1024);
    // W_comb[n][k] = sum_r W_dt[r][n] * W_x[k][r]  -> wt_big rows 0..1023
    for (int i = 0; i < 4; i++)
        gemm_bf16<64, 64, false, 0, false, false, true><<<dim3(16, 16), blk, 0, stream>>>(
            wt_dt + (size_t)i * 1024 * 32, 32, wxb + (size_t)i * 1024 * 64, 64,
            nullptr, nullptr, 0, nullptr, 0, wt_big + (size_t)i * 1088 * 1024, 1024,
            1024, 1024, 32);

    // ---- input projection + LN/relu ----
    gemm_bf16<64, 64, false, 0, false, true, false><<<dim3(8, 32), blk, 0, stream>>>(
        xbf, 288, wt_in0, 288, nullptr, nullptr, 0, lnb, 512, nullptr, 0, 2000, 512, 288);
    ln_k<true, false><<<500, blk, 0, stream>>>(lnb, ln_in_g, ln_in_b, h, 2000);

    for (int i = 0; i < 4; i++) {
        const float* Al = A_log + (size_t)i * 16384;
        ln_k<false, true><<<500, blk, 0, stream>>>(h, ln1_g + i * 512, ln1_b + i * 512,
                                                   lnbb, 2000);
        gemm_bf16<64, 128, false, 0, false, false, true><<<dim3(16, 32), blk, 0, stream>>>(
            lnbb, 512, wt_in + (size_t)i * 2048 * 512, 512,
            nullptr, nullptr, 0, nullptr, 0, xzb, 2048, 2000, 2048, 512);
        conv4_silu_k<<<8000, blk, 0, stream>>>(xzb, cwt + i * 4096,
                                               conv_b + i * 1024, xin, xinb);
        // fused xproj+dt: N=1056 (1024 dt | 32 B,C)
        gemm_bf16<64, 64, false, 2, false, false, false><<<dim3(17, 32), blk, 0, stream>>>(
            xinb, 1024, wt_big + (size_t)i * 1088 * 1024, 1024,
            b_dt + i * 1024, proj, 64, dtb, 1024, nullptr, 0, 2000, 1056, 1024);
        scan_part1<<<dim3(64, NC, 2), blk, 0, stream>>>(dtb, xin, proj, Al, hloc, sc);
        scan_combine<<<128, blk, 0, stream>>>(Al, hloc, sc);
        scan_part2<<<dim3(64, NC, 2), blk, 0, stream>>>(dtb, xin, proj, Al, hloc,
                                                        Dp + i * 1024, xzb, ysb);
        gemm_bf16<64, 64, false, 0, true, true, false><<<dim3(8, 32), blk, 0, stream>>>(
            ysb, 1024, wt_mo + (size_t)i * 512 * 1024, 1024,
            nullptr, h, 512, av, 512, nullptr, 0, 2000, 512, 1024);
        ln_k<false, false><<<500, blk, 0, stream>>>(av, ln2_g + i * 512, ln2_b + i * 512,
                                                    lnb, 2000);
        dcconv31_k<<<4000, blk, 0, stream>>>(lnb, av, dcwt + i * 31 * 512,
                                             dc_b + i * 512, h, hb);
    }

    gemm_bf16<64, 64, true, 0, false, true, false><<<dim3(9, 32), blk, 0, stream>>>(
        hb, 512, wt_out, 512, b_out, nullptr, 0, (float*)d_out, 514, nullptr, 0,
        2000, 514, 512);
    mask_k<<<8, blk, 0, stream>>>(lengths, (float*)d_out + 2000 * 514);
}